// Round 5
// baseline (864.220 us; speedup 1.0000x reference)
//
#include <hip/hip_runtime.h>
#include <hip/hip_bf16.h>
#include <math.h>

#define FEAT 64
#define SCAN_CHUNK 2048   // elements per scan block (256 thr x 8)

// ---------------------------------------------------------------------------
// CSR build: degree count -> hierarchical exclusive scan -> scatter
// ---------------------------------------------------------------------------
__global__ void zero_kernel(int* __restrict__ p, int n) {
    int i = blockIdx.x * blockDim.x + threadIdx.x;
    if (i < n) p[i] = 0;
}

__global__ void count_kernel(const int* __restrict__ dst, int* __restrict__ deg, int nE) {
    int i = blockIdx.x * blockDim.x + threadIdx.x;
    if (i < nE) atomicAdd(&deg[dst[i]], 1);
}

__global__ __launch_bounds__(256) void scan_sum_kernel(const int* __restrict__ deg,
                                                       int* __restrict__ bsum, int n) {
    __shared__ int sdata[4];
    int base = blockIdx.x * SCAN_CHUNK;
    int sum = 0;
    for (int i = threadIdx.x; i < SCAN_CHUNK; i += 256) {
        int idx = base + i;
        if (idx < n) sum += deg[idx];
    }
    for (int d = 32; d > 0; d >>= 1) sum += __shfl_down(sum, d);
    if ((threadIdx.x & 63) == 0) sdata[threadIdx.x >> 6] = sum;
    __syncthreads();
    if (threadIdx.x == 0) bsum[blockIdx.x] = sdata[0] + sdata[1] + sdata[2] + sdata[3];
}

__global__ void scan_block_kernel(const int* __restrict__ bsum, int* __restrict__ boff, int nb) {
    int tid = threadIdx.x;
    int own = (tid < nb) ? bsum[tid] : 0;
    int v = own;
    for (int d = 1; d < 64; d <<= 1) {
        int t = __shfl_up(v, d);
        if (tid >= d) v += t;
    }
    if (tid < nb) boff[tid] = v - own;
}

__global__ __launch_bounds__(256) void scan_write_kernel(const int* __restrict__ deg,
                                                         const int* __restrict__ boff,
                                                         int* __restrict__ off, int n, int E) {
    __shared__ int sw[8];
    int b = blockIdx.x;
    int t = threadIdx.x;
    int i0 = b * SCAN_CHUNK + t * 8;
    int local[8];
    int s = 0;
#pragma unroll
    for (int j = 0; j < 8; ++j) {
        int idx = i0 + j;
        local[j] = (idx < n) ? deg[idx] : 0;
        s += local[j];
    }
    int lane = t & 63, w = t >> 6;
    int inc = s;
    for (int d = 1; d < 64; d <<= 1) {
        int tt = __shfl_up(inc, d);
        if (lane >= d) inc += tt;
    }
    if (lane == 63) sw[w] = inc;
    __syncthreads();
    if (t == 0) { int r = 0; for (int k = 0; k < 4; ++k) { int v = sw[k]; sw[k] = r; r += v; } }
    __syncthreads();
    int texc = (inc - s) + sw[w] + boff[b];
#pragma unroll
    for (int j = 0; j < 8; ++j) {
        int idx = i0 + j;
        if (idx < n) off[idx] = texc;
        texc += local[j];
    }
    if (b == 0 && t == 0) off[n] = E;
}

__global__ void scatter_kernel(const int* __restrict__ src, const int* __restrict__ dst,
                               const int* __restrict__ off, int* __restrict__ cursor,
                               int* __restrict__ csr_src, int nE) {
    int i = blockIdx.x * blockDim.x + threadIdx.x;
    if (i < nE) {
        int d = dst[i];
        int p = atomicAdd(&cursor[d], 1);
        csr_src[off[d] + p] = src[i];
    }
}

// ---------------------------------------------------------------------------
// Fold Wr+Ws -> Wc and bl+bs -> bias for all 3 layers
// ---------------------------------------------------------------------------
__global__ void prep_kernel(const float* __restrict__ Wr0, const float* __restrict__ Ws0,
                            const float* __restrict__ bl0, const float* __restrict__ bs0,
                            const float* __restrict__ Wr1, const float* __restrict__ Ws1,
                            const float* __restrict__ bl1, const float* __restrict__ bs1,
                            const float* __restrict__ Wr2, const float* __restrict__ Ws2,
                            const float* __restrict__ bl2, const float* __restrict__ bs2,
                            float* __restrict__ wc, float* __restrict__ bias) {
    int i = blockIdx.x * blockDim.x + threadIdx.x;
    if (i < 3 * FEAT * FEAT) {
        int li = i >> 12, j = i & 4095;
        const float* Wr = (li == 0) ? Wr0 : (li == 1) ? Wr1 : Wr2;
        const float* Ws = (li == 0) ? Ws0 : (li == 1) ? Ws1 : Ws2;
        wc[i] = Wr[j] + Ws[j];
    }
    if (i < 3 * FEAT) {
        int li = i >> 6, j = i & 63;
        const float* bl = (li == 0) ? bl0 : (li == 1) ? bl1 : bl2;
        const float* bs = (li == 0) ? bs0 : (li == 1) ? bs1 : bs2;
        bias[i] = bl[j] + bs[j];
    }
}

// ---------------------------------------------------------------------------
// Max-aggregation: one 16-lane group per node, inner loop unrolled x8
// -> up to 8 independent 256B row loads in flight per group.
// ---------------------------------------------------------------------------
__device__ __forceinline__ float4 max4(float4 a, float4 b) {
    return make_float4(fmaxf(a.x, b.x), fmaxf(a.y, b.y), fmaxf(a.z, b.z), fmaxf(a.w, b.w));
}

__global__ __launch_bounds__(256) void agg_kernel(const float* __restrict__ h,
                                                  const int* __restrict__ off,
                                                  const int* __restrict__ csr_src,
                                                  float* __restrict__ agg, int nNodes) {
    int gid = blockIdx.x * blockDim.x + threadIdx.x;
    int n = gid >> 4;
    int q = gid & 15;
    if (n >= nNodes) return;

    int e0 = off[n], e1 = off[n + 1];
    const float NEG = -INFINITY;
    float4 acc0 = make_float4(NEG, NEG, NEG, NEG);
    float4 acc1 = acc0;
    int e = e0;
    for (; e + 8 <= e1; e += 8) {
        int s0 = csr_src[e],     s1 = csr_src[e + 1], s2 = csr_src[e + 2], s3 = csr_src[e + 3];
        int s4 = csr_src[e + 4], s5 = csr_src[e + 5], s6 = csr_src[e + 6], s7 = csr_src[e + 7];
        float4 v0 = *(const float4*)&h[(size_t)s0 * FEAT + q * 4];
        float4 v1 = *(const float4*)&h[(size_t)s1 * FEAT + q * 4];
        float4 v2 = *(const float4*)&h[(size_t)s2 * FEAT + q * 4];
        float4 v3 = *(const float4*)&h[(size_t)s3 * FEAT + q * 4];
        float4 v4 = *(const float4*)&h[(size_t)s4 * FEAT + q * 4];
        float4 v5 = *(const float4*)&h[(size_t)s5 * FEAT + q * 4];
        float4 v6 = *(const float4*)&h[(size_t)s6 * FEAT + q * 4];
        float4 v7 = *(const float4*)&h[(size_t)s7 * FEAT + q * 4];
        acc0 = max4(acc0, max4(max4(v0, v1), max4(v2, v3)));
        acc1 = max4(acc1, max4(max4(v4, v5), max4(v6, v7)));
    }
    for (; e + 4 <= e1; e += 4) {
        int s0 = csr_src[e], s1 = csr_src[e + 1], s2 = csr_src[e + 2], s3 = csr_src[e + 3];
        float4 v0 = *(const float4*)&h[(size_t)s0 * FEAT + q * 4];
        float4 v1 = *(const float4*)&h[(size_t)s1 * FEAT + q * 4];
        float4 v2 = *(const float4*)&h[(size_t)s2 * FEAT + q * 4];
        float4 v3 = *(const float4*)&h[(size_t)s3 * FEAT + q * 4];
        acc0 = max4(acc0, max4(v0, v1));
        acc1 = max4(acc1, max4(v2, v3));
    }
    for (; e < e1; ++e) {
        int s0 = csr_src[e];
        float4 v0 = *(const float4*)&h[(size_t)s0 * FEAT + q * 4];
        acc0 = max4(acc0, v0);
    }
    float4 acc = max4(acc0, acc1);
    if (e1 == e0) acc = make_float4(0.f, 0.f, 0.f, 0.f);
    *(float4*)&agg[(size_t)n * FEAT + q * 4] = acc;
}

// ---------------------------------------------------------------------------
// Transform: out = relu(agg @ Wl^T + h @ Wc^T + bias), Wc = Wr+Ws.
// lane = node; f-half and node-tile derived ONLY from blockIdx -> weight
// addresses provably wave-uniform -> s_load streams on the SMEM pipe.
// Block = 4 waves x 64 nodes = 256 nodes, all waves share one f-half.
// ---------------------------------------------------------------------------
__global__ __launch_bounds__(256) void transform_kernel(const float* __restrict__ h,
                                                        const float* __restrict__ agg,
                                                        const float* __restrict__ Wl,
                                                        const float* __restrict__ Wc,
                                                        const float* __restrict__ bias,
                                                        float* __restrict__ out, int nNodes) {
    int tile = blockIdx.x >> 1;                 // node tile of 256
    int fh   = (blockIdx.x & 1) * 32;           // f-half: uniform per block
    int n    = tile * 256 + (int)threadIdx.x;   // this thread's node
    int lane_node_valid = (n < nNodes);
    int nc = lane_node_valid ? n : (nNodes - 1);

    const float* __restrict__ ar = agg + (size_t)nc * FEAT;
    const float* __restrict__ hr = h   + (size_t)nc * FEAT;

    float acc[32];
#pragma unroll
    for (int f = 0; f < 32; ++f) acc[f] = bias[fh + f];

#pragma unroll 2
    for (int kc = 0; kc < FEAT; kc += 16) {
        float ra[16], rh[16];
#pragma unroll
        for (int j = 0; j < 16; j += 4) {
            float4 va = *(const float4*)(ar + kc + j);
            float4 vh = *(const float4*)(hr + kc + j);
            ra[j] = va.x; ra[j+1] = va.y; ra[j+2] = va.z; ra[j+3] = va.w;
            rh[j] = vh.x; rh[j+1] = vh.y; rh[j+2] = vh.z; rh[j+3] = vh.w;
        }
#pragma unroll
        for (int f = 0; f < 32; ++f) {
            const float* __restrict__ wlr = Wl + (size_t)(fh + f) * FEAT + kc;  // uniform addr
            const float* __restrict__ wcr = Wc + (size_t)(fh + f) * FEAT + kc;  // uniform addr
#pragma unroll
            for (int j = 0; j < 16; ++j) {
                acc[f] = fmaf(ra[j], wlr[j], acc[f]);
                acc[f] = fmaf(rh[j], wcr[j], acc[f]);
            }
        }
    }

    if (lane_node_valid) {
        float* __restrict__ orow = out + (size_t)n * FEAT + fh;
#pragma unroll
        for (int f = 0; f < 32; f += 4) {
            float4 v = make_float4(fmaxf(acc[f],     0.f), fmaxf(acc[f + 1], 0.f),
                                   fmaxf(acc[f + 2], 0.f), fmaxf(acc[f + 3], 0.f));
            *(float4*)(orow + f) = v;
        }
    }
}

// ---------------------------------------------------------------------------
extern "C" void kernel_launch(void* const* d_in, const int* in_sizes, int n_in,
                              void* d_out, int out_size, void* d_ws, size_t ws_size,
                              hipStream_t stream) {
    const float* x   = (const float*)d_in[0];
    const int* eidx  = (const int*)d_in[1];
    const int N  = in_sizes[0] / FEAT;
    const int E  = in_sizes[1] / 2;
    const int* src = eidx;
    const int* dst = eidx + E;

    const float* Wl[3]; const float* bl[3]; const float* Wr[3];
    const float* Ws[3]; const float* bs[3];
    for (int li = 0; li < 3; ++li) {
        Wl[li] = (const float*)d_in[2 + 5 * li + 0];
        bl[li] = (const float*)d_in[2 + 5 * li + 1];
        Wr[li] = (const float*)d_in[2 + 5 * li + 2];
        Ws[li] = (const float*)d_in[2 + 5 * li + 3];
        bs[li] = (const float*)d_in[2 + 5 * li + 4];
    }

    auto align256 = [](size_t v) { return (v + 255) & ~(size_t)255; };
    char* ws = (char*)d_ws;
    int* off      = (int*)ws;  ws += align256((size_t)(N + 1) * 4);
    int* cursor   = (int*)ws;  ws += align256((size_t)N * 4);
    int* bsum     = (int*)ws;  ws += align256(64 * 4);
    int* boff     = (int*)ws;  ws += align256(64 * 4);
    float* wcbuf  = (float*)ws; ws += align256(3 * FEAT * FEAT * 4);
    float* biasbuf= (float*)ws; ws += align256(3 * FEAT * 4);
    int* csr_src  = (int*)ws;  ws += align256((size_t)E * 4);
    float* aggbuf = (float*)ws; ws += align256((size_t)N * FEAT * 4);
    float* h1     = (float*)ws; ws += align256((size_t)N * FEAT * 4);
    float* h2     = (float*)ws; ws += align256((size_t)N * FEAT * 4);

    const int TB = 256;
    int eBlocks = (E + TB - 1) / TB;
    int nBlocks = (N + TB - 1) / TB;
    int nb = (N + SCAN_CHUNK - 1) / SCAN_CHUNK;

    // ---- CSR build + weight fold ----
    zero_kernel<<<nBlocks, TB, 0, stream>>>(cursor, N);
    count_kernel<<<eBlocks, TB, 0, stream>>>(dst, cursor, E);
    scan_sum_kernel<<<nb, TB, 0, stream>>>(cursor, bsum, N);
    scan_block_kernel<<<1, 64, 0, stream>>>(bsum, boff, nb);
    scan_write_kernel<<<nb, TB, 0, stream>>>(cursor, boff, off, N, E);
    zero_kernel<<<nBlocks, TB, 0, stream>>>(cursor, N);
    scatter_kernel<<<eBlocks, TB, 0, stream>>>(src, dst, off, cursor, csr_src, E);
    prep_kernel<<<(3 * FEAT * FEAT + TB - 1) / TB, TB, 0, stream>>>(
        Wr[0], Ws[0], bl[0], bs[0], Wr[1], Ws[1], bl[1], bs[1],
        Wr[2], Ws[2], bl[2], bs[2], wcbuf, biasbuf);

    int aggBlocks = (N * 16 + TB - 1) / TB;
    int nTiles256 = (N + 255) / 256;
    int trfBlocks = nTiles256 * 2;   // x2 f-halves (blockIdx & 1)

    agg_kernel<<<aggBlocks, TB, 0, stream>>>(x, off, csr_src, aggbuf, N);
    transform_kernel<<<trfBlocks, TB, 0, stream>>>(x, aggbuf, Wl[0], wcbuf + 0 * 4096,
                                                   biasbuf + 0 * 64, h1, N);
    agg_kernel<<<aggBlocks, TB, 0, stream>>>(h1, off, csr_src, aggbuf, N);
    transform_kernel<<<trfBlocks, TB, 0, stream>>>(h1, aggbuf, Wl[1], wcbuf + 1 * 4096,
                                                   biasbuf + 1 * 64, h2, N);
    agg_kernel<<<aggBlocks, TB, 0, stream>>>(h2, off, csr_src, aggbuf, N);
    transform_kernel<<<trfBlocks, TB, 0, stream>>>(h2, aggbuf, Wl[2], wcbuf + 2 * 4096,
                                                   biasbuf + 2 * 64, (float*)d_out, N);
}

// Round 6
// 530.821 us; speedup vs baseline: 1.6281x; 1.6281x over previous
//
#include <hip/hip_runtime.h>
#include <hip/hip_bf16.h>
#include <math.h>

#define FEAT 64
#define SCAN_CHUNK 2048   // elements per scan block (256 thr x 8)

// ---------------------------------------------------------------------------
// CSR build: degree count -> hierarchical exclusive scan -> scatter
// ---------------------------------------------------------------------------
__global__ void zero_kernel(int* __restrict__ p, int n) {
    int i = blockIdx.x * blockDim.x + threadIdx.x;
    if (i < n) p[i] = 0;
}

__global__ void count_kernel(const int* __restrict__ dst, int* __restrict__ deg, int nE) {
    int i = blockIdx.x * blockDim.x + threadIdx.x;
    if (i < nE) atomicAdd(&deg[dst[i]], 1);
}

__global__ __launch_bounds__(256) void scan_sum_kernel(const int* __restrict__ deg,
                                                       int* __restrict__ bsum, int n) {
    __shared__ int sdata[4];
    int base = blockIdx.x * SCAN_CHUNK;
    int sum = 0;
    for (int i = threadIdx.x; i < SCAN_CHUNK; i += 256) {
        int idx = base + i;
        if (idx < n) sum += deg[idx];
    }
    for (int d = 32; d > 0; d >>= 1) sum += __shfl_down(sum, d);
    if ((threadIdx.x & 63) == 0) sdata[threadIdx.x >> 6] = sum;
    __syncthreads();
    if (threadIdx.x == 0) bsum[blockIdx.x] = sdata[0] + sdata[1] + sdata[2] + sdata[3];
}

__global__ void scan_block_kernel(const int* __restrict__ bsum, int* __restrict__ boff, int nb) {
    int tid = threadIdx.x;
    int own = (tid < nb) ? bsum[tid] : 0;
    int v = own;
    for (int d = 1; d < 64; d <<= 1) {
        int t = __shfl_up(v, d);
        if (tid >= d) v += t;
    }
    if (tid < nb) boff[tid] = v - own;
}

__global__ __launch_bounds__(256) void scan_write_kernel(const int* __restrict__ deg,
                                                         const int* __restrict__ boff,
                                                         int* __restrict__ off, int n, int E) {
    __shared__ int sw[8];
    int b = blockIdx.x;
    int t = threadIdx.x;
    int i0 = b * SCAN_CHUNK + t * 8;
    int local[8];
    int s = 0;
#pragma unroll
    for (int j = 0; j < 8; ++j) {
        int idx = i0 + j;
        local[j] = (idx < n) ? deg[idx] : 0;
        s += local[j];
    }
    int lane = t & 63, w = t >> 6;
    int inc = s;
    for (int d = 1; d < 64; d <<= 1) {
        int tt = __shfl_up(inc, d);
        if (lane >= d) inc += tt;
    }
    if (lane == 63) sw[w] = inc;
    __syncthreads();
    if (t == 0) { int r = 0; for (int k = 0; k < 4; ++k) { int v = sw[k]; sw[k] = r; r += v; } }
    __syncthreads();
    int texc = (inc - s) + sw[w] + boff[b];
#pragma unroll
    for (int j = 0; j < 8; ++j) {
        int idx = i0 + j;
        if (idx < n) off[idx] = texc;
        texc += local[j];
    }
    if (b == 0 && t == 0) off[n] = E;
}

__global__ void scatter_kernel(const int* __restrict__ src, const int* __restrict__ dst,
                               const int* __restrict__ off, int* __restrict__ cursor,
                               int* __restrict__ csr_src, int nE) {
    int i = blockIdx.x * blockDim.x + threadIdx.x;
    if (i < nE) {
        int d = dst[i];
        int p = atomicAdd(&cursor[d], 1);
        csr_src[off[d] + p] = src[i];
    }
}

// ---------------------------------------------------------------------------
// Fold Wr+Ws -> Wc and bl+bs -> bias for all 3 layers
// ---------------------------------------------------------------------------
__global__ void prep_kernel(const float* __restrict__ Wr0, const float* __restrict__ Ws0,
                            const float* __restrict__ bl0, const float* __restrict__ bs0,
                            const float* __restrict__ Wr1, const float* __restrict__ Ws1,
                            const float* __restrict__ bl1, const float* __restrict__ bs1,
                            const float* __restrict__ Wr2, const float* __restrict__ Ws2,
                            const float* __restrict__ bl2, const float* __restrict__ bs2,
                            float* __restrict__ wc, float* __restrict__ bias) {
    int i = blockIdx.x * blockDim.x + threadIdx.x;
    if (i < 3 * FEAT * FEAT) {
        int li = i >> 12, j = i & 4095;
        const float* Wr = (li == 0) ? Wr0 : (li == 1) ? Wr1 : Wr2;
        const float* Ws = (li == 0) ? Ws0 : (li == 1) ? Ws1 : Ws2;
        wc[i] = Wr[j] + Ws[j];
    }
    if (i < 3 * FEAT) {
        int li = i >> 6, j = i & 63;
        const float* bl = (li == 0) ? bl0 : (li == 1) ? bl1 : bl2;
        const float* bs = (li == 0) ? bs0 : (li == 1) ? bs1 : bs2;
        bias[i] = bl[j] + bs[j];
    }
}

// ---------------------------------------------------------------------------
// Max-aggregation: one 16-lane group per node, inner loop unrolled x8.
// ---------------------------------------------------------------------------
__device__ __forceinline__ float4 max4(float4 a, float4 b) {
    return make_float4(fmaxf(a.x, b.x), fmaxf(a.y, b.y), fmaxf(a.z, b.z), fmaxf(a.w, b.w));
}

__global__ __launch_bounds__(256) void agg_kernel(const float* __restrict__ h,
                                                  const int* __restrict__ off,
                                                  const int* __restrict__ csr_src,
                                                  float* __restrict__ agg, int nNodes) {
    int gid = blockIdx.x * blockDim.x + threadIdx.x;
    int n = gid >> 4;
    int q = gid & 15;
    if (n >= nNodes) return;

    int e0 = off[n], e1 = off[n + 1];
    const float NEG = -INFINITY;
    float4 acc0 = make_float4(NEG, NEG, NEG, NEG);
    float4 acc1 = acc0;
    int e = e0;
    for (; e + 8 <= e1; e += 8) {
        int s0 = csr_src[e],     s1 = csr_src[e + 1], s2 = csr_src[e + 2], s3 = csr_src[e + 3];
        int s4 = csr_src[e + 4], s5 = csr_src[e + 5], s6 = csr_src[e + 6], s7 = csr_src[e + 7];
        float4 v0 = *(const float4*)&h[(size_t)s0 * FEAT + q * 4];
        float4 v1 = *(const float4*)&h[(size_t)s1 * FEAT + q * 4];
        float4 v2 = *(const float4*)&h[(size_t)s2 * FEAT + q * 4];
        float4 v3 = *(const float4*)&h[(size_t)s3 * FEAT + q * 4];
        float4 v4 = *(const float4*)&h[(size_t)s4 * FEAT + q * 4];
        float4 v5 = *(const float4*)&h[(size_t)s5 * FEAT + q * 4];
        float4 v6 = *(const float4*)&h[(size_t)s6 * FEAT + q * 4];
        float4 v7 = *(const float4*)&h[(size_t)s7 * FEAT + q * 4];
        acc0 = max4(acc0, max4(max4(v0, v1), max4(v2, v3)));
        acc1 = max4(acc1, max4(max4(v4, v5), max4(v6, v7)));
    }
    for (; e + 4 <= e1; e += 4) {
        int s0 = csr_src[e], s1 = csr_src[e + 1], s2 = csr_src[e + 2], s3 = csr_src[e + 3];
        float4 v0 = *(const float4*)&h[(size_t)s0 * FEAT + q * 4];
        float4 v1 = *(const float4*)&h[(size_t)s1 * FEAT + q * 4];
        float4 v2 = *(const float4*)&h[(size_t)s2 * FEAT + q * 4];
        float4 v3 = *(const float4*)&h[(size_t)s3 * FEAT + q * 4];
        acc0 = max4(acc0, max4(v0, v1));
        acc1 = max4(acc1, max4(v2, v3));
    }
    for (; e < e1; ++e) {
        int s0 = csr_src[e];
        float4 v0 = *(const float4*)&h[(size_t)s0 * FEAT + q * 4];
        acc0 = max4(acc0, v0);
    }
    float4 acc = max4(acc0, acc1);
    if (e1 == e0) acc = make_float4(0.f, 0.f, 0.f, 0.f);
    *(float4*)&agg[(size_t)n * FEAT + q * 4] = acc;
}

// ---------------------------------------------------------------------------
// Transform: out = relu(agg @ Wl^T + h @ Wc^T + bias), Wc = Wr+Ws.
// lane = node; weights staged in LDS, read with WAVE-UNIFORM addresses ->
// hardware broadcast (no bank conflict, no per-lane traffic). One block per
// 256-node tile computes all 64 output features (rows read exactly once).
// ---------------------------------------------------------------------------
__global__ __launch_bounds__(256) void transform_kernel(const float* __restrict__ h,
                                                        const float* __restrict__ agg,
                                                        const float* __restrict__ Wl,
                                                        const float* __restrict__ Wc,
                                                        const float* __restrict__ bias,
                                                        float* __restrict__ out, int nNodes) {
    __shared__ __align__(16) float wl_s[FEAT * FEAT];
    __shared__ __align__(16) float wc_s[FEAT * FEAT];
    __shared__ __align__(16) float b_s[FEAT];

    int tid = threadIdx.x;
    // stage weights: 1024 float4 per matrix, 4 per thread
#pragma unroll
    for (int i = 0; i < 4; ++i) {
        int idx = (tid + i * 256) * 4;
        *(float4*)&wl_s[idx] = *(const float4*)&Wl[idx];
        *(float4*)&wc_s[idx] = *(const float4*)&Wc[idx];
    }
    if (tid < FEAT) b_s[tid] = bias[tid];
    __syncthreads();

    int n = blockIdx.x * 256 + tid;
    bool valid = (n < nNodes);
    int nc = valid ? n : (nNodes - 1);
    const float* __restrict__ ar = agg + (size_t)nc * FEAT;
    const float* __restrict__ hr = h   + (size_t)nc * FEAT;

    float acc[FEAT];
#pragma unroll
    for (int f = 0; f < FEAT; ++f) acc[f] = b_s[f];   // uniform-addr broadcast

#pragma unroll 1
    for (int kc = 0; kc < FEAT; kc += 8) {
        float4 a0 = *(const float4*)(ar + kc);
        float4 a1 = *(const float4*)(ar + kc + 4);
        float4 h0 = *(const float4*)(hr + kc);
        float4 h1 = *(const float4*)(hr + kc + 4);
        float ra[8] = {a0.x, a0.y, a0.z, a0.w, a1.x, a1.y, a1.z, a1.w};
        float rh[8] = {h0.x, h0.y, h0.z, h0.w, h1.x, h1.y, h1.z, h1.w};
#pragma unroll
        for (int f = 0; f < FEAT; ++f) {
            float4 wl0 = *(const float4*)&wl_s[f * FEAT + kc];      // uniform
            float4 wl1 = *(const float4*)&wl_s[f * FEAT + kc + 4];  // uniform
            float4 wc0 = *(const float4*)&wc_s[f * FEAT + kc];      // uniform
            float4 wc1 = *(const float4*)&wc_s[f * FEAT + kc + 4];  // uniform
            float a = acc[f];
            a = fmaf(ra[0], wl0.x, a); a = fmaf(ra[1], wl0.y, a);
            a = fmaf(ra[2], wl0.z, a); a = fmaf(ra[3], wl0.w, a);
            a = fmaf(ra[4], wl1.x, a); a = fmaf(ra[5], wl1.y, a);
            a = fmaf(ra[6], wl1.z, a); a = fmaf(ra[7], wl1.w, a);
            a = fmaf(rh[0], wc0.x, a); a = fmaf(rh[1], wc0.y, a);
            a = fmaf(rh[2], wc0.z, a); a = fmaf(rh[3], wc0.w, a);
            a = fmaf(rh[4], wc1.x, a); a = fmaf(rh[5], wc1.y, a);
            a = fmaf(rh[6], wc1.z, a); a = fmaf(rh[7], wc1.w, a);
            acc[f] = a;
        }
    }

    if (valid) {
        float* __restrict__ orow = out + (size_t)n * FEAT;
#pragma unroll
        for (int f = 0; f < FEAT; f += 4) {
            float4 v = make_float4(fmaxf(acc[f],     0.f), fmaxf(acc[f + 1], 0.f),
                                   fmaxf(acc[f + 2], 0.f), fmaxf(acc[f + 3], 0.f));
            *(float4*)(orow + f) = v;
        }
    }
}

// ---------------------------------------------------------------------------
extern "C" void kernel_launch(void* const* d_in, const int* in_sizes, int n_in,
                              void* d_out, int out_size, void* d_ws, size_t ws_size,
                              hipStream_t stream) {
    const float* x   = (const float*)d_in[0];
    const int* eidx  = (const int*)d_in[1];
    const int N  = in_sizes[0] / FEAT;
    const int E  = in_sizes[1] / 2;
    const int* src = eidx;
    const int* dst = eidx + E;

    const float* Wl[3]; const float* bl[3]; const float* Wr[3];
    const float* Ws[3]; const float* bs[3];
    for (int li = 0; li < 3; ++li) {
        Wl[li] = (const float*)d_in[2 + 5 * li + 0];
        bl[li] = (const float*)d_in[2 + 5 * li + 1];
        Wr[li] = (const float*)d_in[2 + 5 * li + 2];
        Ws[li] = (const float*)d_in[2 + 5 * li + 3];
        bs[li] = (const float*)d_in[2 + 5 * li + 4];
    }

    auto align256 = [](size_t v) { return (v + 255) & ~(size_t)255; };
    char* ws = (char*)d_ws;
    int* off      = (int*)ws;  ws += align256((size_t)(N + 1) * 4);
    int* cursor   = (int*)ws;  ws += align256((size_t)N * 4);
    int* bsum     = (int*)ws;  ws += align256(64 * 4);
    int* boff     = (int*)ws;  ws += align256(64 * 4);
    float* wcbuf  = (float*)ws; ws += align256(3 * FEAT * FEAT * 4);
    float* biasbuf= (float*)ws; ws += align256(3 * FEAT * 4);
    int* csr_src  = (int*)ws;  ws += align256((size_t)E * 4);
    float* aggbuf = (float*)ws; ws += align256((size_t)N * FEAT * 4);
    float* h1     = (float*)ws; ws += align256((size_t)N * FEAT * 4);
    float* h2     = (float*)ws; ws += align256((size_t)N * FEAT * 4);

    const int TB = 256;
    int eBlocks = (E + TB - 1) / TB;
    int nBlocks = (N + TB - 1) / TB;
    int nb = (N + SCAN_CHUNK - 1) / SCAN_CHUNK;

    // ---- CSR build + weight fold ----
    zero_kernel<<<nBlocks, TB, 0, stream>>>(cursor, N);
    count_kernel<<<eBlocks, TB, 0, stream>>>(dst, cursor, E);
    scan_sum_kernel<<<nb, TB, 0, stream>>>(cursor, bsum, N);
    scan_block_kernel<<<1, 64, 0, stream>>>(bsum, boff, nb);
    scan_write_kernel<<<nb, TB, 0, stream>>>(cursor, boff, off, N, E);
    zero_kernel<<<nBlocks, TB, 0, stream>>>(cursor, N);
    scatter_kernel<<<eBlocks, TB, 0, stream>>>(src, dst, off, cursor, csr_src, E);
    prep_kernel<<<(3 * FEAT * FEAT + TB - 1) / TB, TB, 0, stream>>>(
        Wr[0], Ws[0], bl[0], bs[0], Wr[1], Ws[1], bl[1], bs[1],
        Wr[2], Ws[2], bl[2], bs[2], wcbuf, biasbuf);

    int aggBlocks = (N * 16 + TB - 1) / TB;
    int trfBlocks = (N + 255) / 256;   // one block per 256-node tile, all 64 f

    agg_kernel<<<aggBlocks, TB, 0, stream>>>(x, off, csr_src, aggbuf, N);
    transform_kernel<<<trfBlocks, TB, 0, stream>>>(x, aggbuf, Wl[0], wcbuf + 0 * 4096,
                                                   biasbuf + 0 * 64, h1, N);
    agg_kernel<<<aggBlocks, TB, 0, stream>>>(h1, off, csr_src, aggbuf, N);
    transform_kernel<<<trfBlocks, TB, 0, stream>>>(h1, aggbuf, Wl[1], wcbuf + 1 * 4096,
                                                   biasbuf + 1 * 64, h2, N);
    agg_kernel<<<aggBlocks, TB, 0, stream>>>(h2, off, csr_src, aggbuf, N);
    transform_kernel<<<trfBlocks, TB, 0, stream>>>(h2, aggbuf, Wl[2], wcbuf + 2 * 4096,
                                                   biasbuf + 2 * 64, (float*)d_out, N);
}

// Round 7
// 495.023 us; speedup vs baseline: 1.7458x; 1.0723x over previous
//
#include <hip/hip_runtime.h>
#include <hip/hip_bf16.h>
#include <math.h>

#define FEAT 64
#define SCAN_CHUNK 2048   // elements per scan block (256 thr x 8)
#define NXCD 8
#define NCHUNKS 1024      // edge chunks per dst-range

// ---------------------------------------------------------------------------
// CSR build: XCD-range-partitioned count -> hierarchical scan -> partitioned
// scatter. dst-range r is only touched by blocks with blockIdx%8==r (which
// dispatch round-robin onto XCD r) -> cursor atomics and csr-line writes stay
// XCD-local and merge in that XCD's L2.
// ---------------------------------------------------------------------------
__global__ void zero_kernel(int* __restrict__ p, int n) {
    int i = blockIdx.x * blockDim.x + threadIdx.x;
    if (i < n) p[i] = 0;
}

__global__ __launch_bounds__(256) void count_part_kernel(const int* __restrict__ dst,
                                                         int* __restrict__ deg,
                                                         int nE, int nN) {
    int r = blockIdx.x & (NXCD - 1);
    int c = blockIdx.x >> 3;
    int rangeSize = (nN + NXCD - 1) / NXCD;
    int lo = r * rangeSize;
    int hi = lo + rangeSize; if (hi > nN) hi = nN;
    int chunk = (nE + NCHUNKS - 1) / NCHUNKS;
    int begin = c * chunk;
    int end = begin + chunk; if (end > nE) end = nE;
    for (int i = begin + (int)threadIdx.x; i < end; i += 256) {
        int d = dst[i];
        if (d >= lo && d < hi) atomicAdd(&deg[d], 1);
    }
}

__global__ __launch_bounds__(256) void scatter_part_kernel(const int* __restrict__ src,
                                                           const int* __restrict__ dst,
                                                           const int* __restrict__ off,
                                                           int* __restrict__ cursor,
                                                           int* __restrict__ csr_src,
                                                           int nE, int nN) {
    int r = blockIdx.x & (NXCD - 1);
    int c = blockIdx.x >> 3;
    int rangeSize = (nN + NXCD - 1) / NXCD;
    int lo = r * rangeSize;
    int hi = lo + rangeSize; if (hi > nN) hi = nN;
    int chunk = (nE + NCHUNKS - 1) / NCHUNKS;
    int begin = c * chunk;
    int end = begin + chunk; if (end > nE) end = nE;
    for (int i = begin + (int)threadIdx.x; i < end; i += 256) {
        int d = dst[i];
        if (d >= lo && d < hi) {
            int p = atomicAdd(&cursor[d], 1);
            csr_src[off[d] + p] = src[i];
        }
    }
}

__global__ __launch_bounds__(256) void scan_sum_kernel(const int* __restrict__ deg,
                                                       int* __restrict__ bsum, int n) {
    __shared__ int sdata[4];
    int base = blockIdx.x * SCAN_CHUNK;
    int sum = 0;
    for (int i = threadIdx.x; i < SCAN_CHUNK; i += 256) {
        int idx = base + i;
        if (idx < n) sum += deg[idx];
    }
    for (int d = 32; d > 0; d >>= 1) sum += __shfl_down(sum, d);
    if ((threadIdx.x & 63) == 0) sdata[threadIdx.x >> 6] = sum;
    __syncthreads();
    if (threadIdx.x == 0) bsum[blockIdx.x] = sdata[0] + sdata[1] + sdata[2] + sdata[3];
}

__global__ void scan_block_kernel(const int* __restrict__ bsum, int* __restrict__ boff, int nb) {
    int tid = threadIdx.x;
    int own = (tid < nb) ? bsum[tid] : 0;
    int v = own;
    for (int d = 1; d < 64; d <<= 1) {
        int t = __shfl_up(v, d);
        if (tid >= d) v += t;
    }
    if (tid < nb) boff[tid] = v - own;
}

__global__ __launch_bounds__(256) void scan_write_kernel(const int* __restrict__ deg,
                                                         const int* __restrict__ boff,
                                                         int* __restrict__ off, int n, int E) {
    __shared__ int sw[8];
    int b = blockIdx.x;
    int t = threadIdx.x;
    int i0 = b * SCAN_CHUNK + t * 8;
    int local[8];
    int s = 0;
#pragma unroll
    for (int j = 0; j < 8; ++j) {
        int idx = i0 + j;
        local[j] = (idx < n) ? deg[idx] : 0;
        s += local[j];
    }
    int lane = t & 63, w = t >> 6;
    int inc = s;
    for (int d = 1; d < 64; d <<= 1) {
        int tt = __shfl_up(inc, d);
        if (lane >= d) inc += tt;
    }
    if (lane == 63) sw[w] = inc;
    __syncthreads();
    if (t == 0) { int r = 0; for (int k = 0; k < 4; ++k) { int v = sw[k]; sw[k] = r; r += v; } }
    __syncthreads();
    int texc = (inc - s) + sw[w] + boff[b];
#pragma unroll
    for (int j = 0; j < 8; ++j) {
        int idx = i0 + j;
        if (idx < n) off[idx] = texc;
        texc += local[j];
    }
    if (b == 0 && t == 0) off[n] = E;
}

// ---------------------------------------------------------------------------
// Fold Wr+Ws -> Wc and bl+bs -> bias for all 3 layers
// ---------------------------------------------------------------------------
__global__ void prep_kernel(const float* __restrict__ Wr0, const float* __restrict__ Ws0,
                            const float* __restrict__ bl0, const float* __restrict__ bs0,
                            const float* __restrict__ Wr1, const float* __restrict__ Ws1,
                            const float* __restrict__ bl1, const float* __restrict__ bs1,
                            const float* __restrict__ Wr2, const float* __restrict__ Ws2,
                            const float* __restrict__ bl2, const float* __restrict__ bs2,
                            float* __restrict__ wc, float* __restrict__ bias) {
    int i = blockIdx.x * blockDim.x + threadIdx.x;
    if (i < 3 * FEAT * FEAT) {
        int li = i >> 12, j = i & 4095;
        const float* Wr = (li == 0) ? Wr0 : (li == 1) ? Wr1 : Wr2;
        const float* Ws = (li == 0) ? Ws0 : (li == 1) ? Ws1 : Ws2;
        wc[i] = Wr[j] + Ws[j];
    }
    if (i < 3 * FEAT) {
        int li = i >> 6, j = i & 63;
        const float* bl = (li == 0) ? bl0 : (li == 1) ? bl1 : bl2;
        const float* bs = (li == 0) ? bs0 : (li == 1) ? bs1 : bs2;
        bias[i] = bl[j] + bs[j];
    }
}

// ---------------------------------------------------------------------------
// Max-aggregation: one 16-lane group per node, inner loop unrolled x8.
// ---------------------------------------------------------------------------
__device__ __forceinline__ float4 max4(float4 a, float4 b) {
    return make_float4(fmaxf(a.x, b.x), fmaxf(a.y, b.y), fmaxf(a.z, b.z), fmaxf(a.w, b.w));
}

__global__ __launch_bounds__(256) void agg_kernel(const float* __restrict__ h,
                                                  const int* __restrict__ off,
                                                  const int* __restrict__ csr_src,
                                                  float* __restrict__ agg, int nNodes) {
    int gid = blockIdx.x * blockDim.x + threadIdx.x;
    int n = gid >> 4;
    int q = gid & 15;
    if (n >= nNodes) return;

    int e0 = off[n], e1 = off[n + 1];
    const float NEG = -INFINITY;
    float4 acc0 = make_float4(NEG, NEG, NEG, NEG);
    float4 acc1 = acc0;
    int e = e0;
    for (; e + 8 <= e1; e += 8) {
        int s0 = csr_src[e],     s1 = csr_src[e + 1], s2 = csr_src[e + 2], s3 = csr_src[e + 3];
        int s4 = csr_src[e + 4], s5 = csr_src[e + 5], s6 = csr_src[e + 6], s7 = csr_src[e + 7];
        float4 v0 = *(const float4*)&h[(size_t)s0 * FEAT + q * 4];
        float4 v1 = *(const float4*)&h[(size_t)s1 * FEAT + q * 4];
        float4 v2 = *(const float4*)&h[(size_t)s2 * FEAT + q * 4];
        float4 v3 = *(const float4*)&h[(size_t)s3 * FEAT + q * 4];
        float4 v4 = *(const float4*)&h[(size_t)s4 * FEAT + q * 4];
        float4 v5 = *(const float4*)&h[(size_t)s5 * FEAT + q * 4];
        float4 v6 = *(const float4*)&h[(size_t)s6 * FEAT + q * 4];
        float4 v7 = *(const float4*)&h[(size_t)s7 * FEAT + q * 4];
        acc0 = max4(acc0, max4(max4(v0, v1), max4(v2, v3)));
        acc1 = max4(acc1, max4(max4(v4, v5), max4(v6, v7)));
    }
    for (; e + 4 <= e1; e += 4) {
        int s0 = csr_src[e], s1 = csr_src[e + 1], s2 = csr_src[e + 2], s3 = csr_src[e + 3];
        float4 v0 = *(const float4*)&h[(size_t)s0 * FEAT + q * 4];
        float4 v1 = *(const float4*)&h[(size_t)s1 * FEAT + q * 4];
        float4 v2 = *(const float4*)&h[(size_t)s2 * FEAT + q * 4];
        float4 v3 = *(const float4*)&h[(size_t)s3 * FEAT + q * 4];
        acc0 = max4(acc0, max4(v0, v1));
        acc1 = max4(acc1, max4(v2, v3));
    }
    for (; e < e1; ++e) {
        int s0 = csr_src[e];
        float4 v0 = *(const float4*)&h[(size_t)s0 * FEAT + q * 4];
        acc0 = max4(acc0, v0);
    }
    float4 acc = max4(acc0, acc1);
    if (e1 == e0) acc = make_float4(0.f, 0.f, 0.f, 0.f);
    *(float4*)&agg[(size_t)n * FEAT + q * 4] = acc;
}

// ---------------------------------------------------------------------------
// Transform: out = relu(agg @ Wl^T + h @ Wc^T + bias), Wc = Wr+Ws.
// thread = node; weights staged in LDS, wave-uniform ds_read -> broadcast.
// ---------------------------------------------------------------------------
__global__ __launch_bounds__(256) void transform_kernel(const float* __restrict__ h,
                                                        const float* __restrict__ agg,
                                                        const float* __restrict__ Wl,
                                                        const float* __restrict__ Wc,
                                                        const float* __restrict__ bias,
                                                        float* __restrict__ out, int nNodes) {
    __shared__ __align__(16) float wl_s[FEAT * FEAT];
    __shared__ __align__(16) float wc_s[FEAT * FEAT];
    __shared__ __align__(16) float b_s[FEAT];

    int tid = threadIdx.x;
#pragma unroll
    for (int i = 0; i < 4; ++i) {
        int idx = (tid + i * 256) * 4;
        *(float4*)&wl_s[idx] = *(const float4*)&Wl[idx];
        *(float4*)&wc_s[idx] = *(const float4*)&Wc[idx];
    }
    if (tid < FEAT) b_s[tid] = bias[tid];
    __syncthreads();

    int n = blockIdx.x * 256 + tid;
    bool valid = (n < nNodes);
    int nc = valid ? n : (nNodes - 1);
    const float* __restrict__ ar = agg + (size_t)nc * FEAT;
    const float* __restrict__ hr = h   + (size_t)nc * FEAT;

    float acc[FEAT];
#pragma unroll
    for (int f = 0; f < FEAT; ++f) acc[f] = b_s[f];

#pragma unroll 1
    for (int kc = 0; kc < FEAT; kc += 8) {
        float4 a0 = *(const float4*)(ar + kc);
        float4 a1 = *(const float4*)(ar + kc + 4);
        float4 h0 = *(const float4*)(hr + kc);
        float4 h1 = *(const float4*)(hr + kc + 4);
        float ra[8] = {a0.x, a0.y, a0.z, a0.w, a1.x, a1.y, a1.z, a1.w};
        float rh[8] = {h0.x, h0.y, h0.z, h0.w, h1.x, h1.y, h1.z, h1.w};
#pragma unroll
        for (int f = 0; f < FEAT; ++f) {
            float4 wl0 = *(const float4*)&wl_s[f * FEAT + kc];
            float4 wl1 = *(const float4*)&wl_s[f * FEAT + kc + 4];
            float4 wc0 = *(const float4*)&wc_s[f * FEAT + kc];
            float4 wc1 = *(const float4*)&wc_s[f * FEAT + kc + 4];
            float a = acc[f];
            a = fmaf(ra[0], wl0.x, a); a = fmaf(ra[1], wl0.y, a);
            a = fmaf(ra[2], wl0.z, a); a = fmaf(ra[3], wl0.w, a);
            a = fmaf(ra[4], wl1.x, a); a = fmaf(ra[5], wl1.y, a);
            a = fmaf(ra[6], wl1.z, a); a = fmaf(ra[7], wl1.w, a);
            a = fmaf(rh[0], wc0.x, a); a = fmaf(rh[1], wc0.y, a);
            a = fmaf(rh[2], wc0.z, a); a = fmaf(rh[3], wc0.w, a);
            a = fmaf(rh[4], wc1.x, a); a = fmaf(rh[5], wc1.y, a);
            a = fmaf(rh[6], wc1.z, a); a = fmaf(rh[7], wc1.w, a);
            acc[f] = a;
        }
    }

    if (valid) {
        float* __restrict__ orow = out + (size_t)n * FEAT;
#pragma unroll
        for (int f = 0; f < FEAT; f += 4) {
            float4 v = make_float4(fmaxf(acc[f],     0.f), fmaxf(acc[f + 1], 0.f),
                                   fmaxf(acc[f + 2], 0.f), fmaxf(acc[f + 3], 0.f));
            *(float4*)(orow + f) = v;
        }
    }
}

// ---------------------------------------------------------------------------
extern "C" void kernel_launch(void* const* d_in, const int* in_sizes, int n_in,
                              void* d_out, int out_size, void* d_ws, size_t ws_size,
                              hipStream_t stream) {
    const float* x   = (const float*)d_in[0];
    const int* eidx  = (const int*)d_in[1];
    const int N  = in_sizes[0] / FEAT;
    const int E  = in_sizes[1] / 2;
    const int* src = eidx;
    const int* dst = eidx + E;

    const float* Wl[3]; const float* bl[3]; const float* Wr[3];
    const float* Ws[3]; const float* bs[3];
    for (int li = 0; li < 3; ++li) {
        Wl[li] = (const float*)d_in[2 + 5 * li + 0];
        bl[li] = (const float*)d_in[2 + 5 * li + 1];
        Wr[li] = (const float*)d_in[2 + 5 * li + 2];
        Ws[li] = (const float*)d_in[2 + 5 * li + 3];
        bs[li] = (const float*)d_in[2 + 5 * li + 4];
    }

    auto align256 = [](size_t v) { return (v + 255) & ~(size_t)255; };
    char* ws = (char*)d_ws;
    int* off      = (int*)ws;  ws += align256((size_t)(N + 1) * 4);
    int* cursor   = (int*)ws;  ws += align256((size_t)N * 4);
    int* bsum     = (int*)ws;  ws += align256(64 * 4);
    int* boff     = (int*)ws;  ws += align256(64 * 4);
    float* wcbuf  = (float*)ws; ws += align256(3 * FEAT * FEAT * 4);
    float* biasbuf= (float*)ws; ws += align256(3 * FEAT * 4);
    int* csr_src  = (int*)ws;  ws += align256((size_t)E * 4);
    float* aggbuf = (float*)ws; ws += align256((size_t)N * FEAT * 4);
    float* h1     = (float*)ws; ws += align256((size_t)N * FEAT * 4);
    float* h2     = (float*)ws; ws += align256((size_t)N * FEAT * 4);

    const int TB = 256;
    int nBlocks = (N + TB - 1) / TB;
    int nb = (N + SCAN_CHUNK - 1) / SCAN_CHUNK;
    int partBlocks = NXCD * NCHUNKS;

    // ---- CSR build (XCD-range-partitioned) + weight fold ----
    zero_kernel<<<nBlocks, TB, 0, stream>>>(cursor, N);
    count_part_kernel<<<partBlocks, TB, 0, stream>>>(dst, cursor, E, N);
    scan_sum_kernel<<<nb, TB, 0, stream>>>(cursor, bsum, N);
    scan_block_kernel<<<1, 64, 0, stream>>>(bsum, boff, nb);
    scan_write_kernel<<<nb, TB, 0, stream>>>(cursor, boff, off, N, E);
    zero_kernel<<<nBlocks, TB, 0, stream>>>(cursor, N);
    scatter_part_kernel<<<partBlocks, TB, 0, stream>>>(src, dst, off, cursor, csr_src, E, N);
    prep_kernel<<<(3 * FEAT * FEAT + TB - 1) / TB, TB, 0, stream>>>(
        Wr[0], Ws[0], bl[0], bs[0], Wr[1], Ws[1], bl[1], bs[1],
        Wr[2], Ws[2], bl[2], bs[2], wcbuf, biasbuf);

    int aggBlocks = (N * 16 + TB - 1) / TB;
    int trfBlocks = (N + 255) / 256;

    agg_kernel<<<aggBlocks, TB, 0, stream>>>(x, off, csr_src, aggbuf, N);
    transform_kernel<<<trfBlocks, TB, 0, stream>>>(x, aggbuf, Wl[0], wcbuf + 0 * 4096,
                                                   biasbuf + 0 * 64, h1, N);
    agg_kernel<<<aggBlocks, TB, 0, stream>>>(h1, off, csr_src, aggbuf, N);
    transform_kernel<<<trfBlocks, TB, 0, stream>>>(h1, aggbuf, Wl[1], wcbuf + 1 * 4096,
                                                   biasbuf + 1 * 64, h2, N);
    agg_kernel<<<aggBlocks, TB, 0, stream>>>(h2, off, csr_src, aggbuf, N);
    transform_kernel<<<trfBlocks, TB, 0, stream>>>(h2, aggbuf, Wl[2], wcbuf + 2 * 4096,
                                                   biasbuf + 2 * 64, (float*)d_out, N);
}

// Round 8
// 415.755 us; speedup vs baseline: 2.0787x; 1.1907x over previous
//
#include <hip/hip_runtime.h>
#include <hip/hip_bf16.h>
#include <math.h>

#define FEAT 64
#define SCAN_CHUNK 2048
#define NXCD 8
#define NCHUNKS 1024

// ---- bf16 helpers (RNE pack, exact unpack) --------------------------------
__device__ __forceinline__ float bf_lo(unsigned u) { return __uint_as_float(u << 16); }
__device__ __forceinline__ float bf_hi(unsigned u) { return __uint_as_float(u & 0xFFFF0000u); }
__device__ __forceinline__ unsigned short f2bf(float f) {          // round-nearest-even
    unsigned b = __float_as_uint(f);
    return (unsigned short)((b + 0x7FFFu + ((b >> 16) & 1u)) >> 16);
}
// exact pack of two values that are already bf16-representable
__device__ __forceinline__ unsigned pack_exact(float lo, float hi) {
    return (__float_as_uint(lo) >> 16) | (__float_as_uint(hi) & 0xFFFF0000u);
}

// ---------------------------------------------------------------------------
// CSR build (XCD-range-partitioned, as round 7)
// ---------------------------------------------------------------------------
__global__ void zero_kernel(int* __restrict__ p, int n) {
    int i = blockIdx.x * blockDim.x + threadIdx.x;
    if (i < n) p[i] = 0;
}

__global__ __launch_bounds__(256) void count_part_kernel(const int* __restrict__ dst,
                                                         int* __restrict__ deg,
                                                         int nE, int nN) {
    int r = blockIdx.x & (NXCD - 1);
    int c = blockIdx.x >> 3;
    int rangeSize = (nN + NXCD - 1) / NXCD;
    int lo = r * rangeSize;
    int hi = lo + rangeSize; if (hi > nN) hi = nN;
    int chunk = (nE + NCHUNKS - 1) / NCHUNKS;
    int begin = c * chunk;
    int end = begin + chunk; if (end > nE) end = nE;
    for (int i = begin + (int)threadIdx.x; i < end; i += 256) {
        int d = dst[i];
        if (d >= lo && d < hi) atomicAdd(&deg[d], 1);
    }
}

__global__ __launch_bounds__(256) void scatter_part_kernel(const int* __restrict__ src,
                                                           const int* __restrict__ dst,
                                                           const int* __restrict__ off,
                                                           int* __restrict__ cursor,
                                                           int* __restrict__ csr_src,
                                                           int nE, int nN) {
    int r = blockIdx.x & (NXCD - 1);
    int c = blockIdx.x >> 3;
    int rangeSize = (nN + NXCD - 1) / NXCD;
    int lo = r * rangeSize;
    int hi = lo + rangeSize; if (hi > nN) hi = nN;
    int chunk = (nE + NCHUNKS - 1) / NCHUNKS;
    int begin = c * chunk;
    int end = begin + chunk; if (end > nE) end = nE;
    for (int i = begin + (int)threadIdx.x; i < end; i += 256) {
        int d = dst[i];
        if (d >= lo && d < hi) {
            int p = atomicAdd(&cursor[d], 1);
            csr_src[off[d] + p] = src[i];
        }
    }
}

__global__ __launch_bounds__(256) void scan_sum_kernel(const int* __restrict__ deg,
                                                       int* __restrict__ bsum, int n) {
    __shared__ int sdata[4];
    int base = blockIdx.x * SCAN_CHUNK;
    int sum = 0;
    for (int i = threadIdx.x; i < SCAN_CHUNK; i += 256) {
        int idx = base + i;
        if (idx < n) sum += deg[idx];
    }
    for (int d = 32; d > 0; d >>= 1) sum += __shfl_down(sum, d);
    if ((threadIdx.x & 63) == 0) sdata[threadIdx.x >> 6] = sum;
    __syncthreads();
    if (threadIdx.x == 0) bsum[blockIdx.x] = sdata[0] + sdata[1] + sdata[2] + sdata[3];
}

__global__ void scan_block_kernel(const int* __restrict__ bsum, int* __restrict__ boff, int nb) {
    int tid = threadIdx.x;
    int own = (tid < nb) ? bsum[tid] : 0;
    int v = own;
    for (int d = 1; d < 64; d <<= 1) {
        int t = __shfl_up(v, d);
        if (tid >= d) v += t;
    }
    if (tid < nb) boff[tid] = v - own;
}

__global__ __launch_bounds__(256) void scan_write_kernel(const int* __restrict__ deg,
                                                         const int* __restrict__ boff,
                                                         int* __restrict__ off, int n, int E) {
    __shared__ int sw[8];
    int b = blockIdx.x;
    int t = threadIdx.x;
    int i0 = b * SCAN_CHUNK + t * 8;
    int local[8];
    int s = 0;
#pragma unroll
    for (int j = 0; j < 8; ++j) {
        int idx = i0 + j;
        local[j] = (idx < n) ? deg[idx] : 0;
        s += local[j];
    }
    int lane = t & 63, w = t >> 6;
    int inc = s;
    for (int d = 1; d < 64; d <<= 1) {
        int tt = __shfl_up(inc, d);
        if (lane >= d) inc += tt;
    }
    if (lane == 63) sw[w] = inc;
    __syncthreads();
    if (t == 0) { int r = 0; for (int k = 0; k < 4; ++k) { int v = sw[k]; sw[k] = r; r += v; } }
    __syncthreads();
    int texc = (inc - s) + sw[w] + boff[b];
#pragma unroll
    for (int j = 0; j < 8; ++j) {
        int idx = i0 + j;
        if (idx < n) off[idx] = texc;
        texc += local[j];
    }
    if (b == 0 && t == 0) off[n] = E;
}

// ---------------------------------------------------------------------------
// prep: Wc = Wr+Ws, bias = bl+bs (f32)
// ---------------------------------------------------------------------------
__global__ void prep_kernel(const float* __restrict__ Wr0, const float* __restrict__ Ws0,
                            const float* __restrict__ bl0, const float* __restrict__ bs0,
                            const float* __restrict__ Wr1, const float* __restrict__ Ws1,
                            const float* __restrict__ bl1, const float* __restrict__ bs1,
                            const float* __restrict__ Wr2, const float* __restrict__ Ws2,
                            const float* __restrict__ bl2, const float* __restrict__ bs2,
                            float* __restrict__ wc, float* __restrict__ bias) {
    int i = blockIdx.x * blockDim.x + threadIdx.x;
    if (i < 3 * FEAT * FEAT) {
        int li = i >> 12, j = i & 4095;
        const float* Wr = (li == 0) ? Wr0 : (li == 1) ? Wr1 : Wr2;
        const float* Ws = (li == 0) ? Ws0 : (li == 1) ? Ws1 : Ws2;
        wc[i] = Wr[j] + Ws[j];
    }
    if (i < 3 * FEAT) {
        int li = i >> 6, j = i & 63;
        const float* bl = (li == 0) ? bl0 : (li == 1) ? bl1 : bl2;
        const float* bs = (li == 0) ? bs0 : (li == 1) ? bs1 : bs2;
        bias[i] = bl[j] + bs[j];
    }
}

// ---------------------------------------------------------------------------
// x (f32) -> xb (bf16), 8 elems/thread
// ---------------------------------------------------------------------------
__global__ __launch_bounds__(256) void conv_kernel(const float* __restrict__ in,
                                                   unsigned short* __restrict__ outb,
                                                   int nElem) {
    int base = (blockIdx.x * blockDim.x + threadIdx.x) * 8;
    if (base >= nElem) return;
    float4 a = *(const float4*)(in + base);
    float4 b = *(const float4*)(in + base + 4);
    ushort4 p0 = {f2bf(a.x), f2bf(a.y), f2bf(a.z), f2bf(a.w)};
    ushort4 p1 = {f2bf(b.x), f2bf(b.y), f2bf(b.z), f2bf(b.w)};
    *(ushort4*)(outb + base) = p0;
    *(ushort4*)(outb + base + 4) = p1;
}

// ---------------------------------------------------------------------------
// Max-aggregation on bf16 rows (128 B/row): 8-lane group per node, each lane
// owns 16 B (8 bf16) of the row; 4 rows in flight per group; no cross-lane
// reduction needed.
// ---------------------------------------------------------------------------
__global__ __launch_bounds__(256) void agg_kernel(const unsigned short* __restrict__ hb,
                                                  const int* __restrict__ off,
                                                  const int* __restrict__ csr_src,
                                                  unsigned short* __restrict__ ab,
                                                  int nNodes) {
    int gid = blockIdx.x * blockDim.x + threadIdx.x;
    int n = gid >> 3;          // node = 8-lane group
    int q = gid & 7;           // 8-bf16 chunk of the row
    if (n >= nNodes) return;

    int e0 = off[n], e1 = off[n + 1];
    const float NEG = -INFINITY;
    float acc[8] = {NEG, NEG, NEG, NEG, NEG, NEG, NEG, NEG};

    int e = e0;
    for (; e + 4 <= e1; e += 4) {
        int s0 = csr_src[e], s1 = csr_src[e + 1], s2 = csr_src[e + 2], s3 = csr_src[e + 3];
        uint4 v0 = *(const uint4*)&hb[(size_t)s0 * FEAT + q * 8];
        uint4 v1 = *(const uint4*)&hb[(size_t)s1 * FEAT + q * 8];
        uint4 v2 = *(const uint4*)&hb[(size_t)s2 * FEAT + q * 8];
        uint4 v3 = *(const uint4*)&hb[(size_t)s3 * FEAT + q * 8];
#define ACCUM(v)                                            \
        acc[0] = fmaxf(acc[0], bf_lo(v.x)); acc[1] = fmaxf(acc[1], bf_hi(v.x)); \
        acc[2] = fmaxf(acc[2], bf_lo(v.y)); acc[3] = fmaxf(acc[3], bf_hi(v.y)); \
        acc[4] = fmaxf(acc[4], bf_lo(v.z)); acc[5] = fmaxf(acc[5], bf_hi(v.z)); \
        acc[6] = fmaxf(acc[6], bf_lo(v.w)); acc[7] = fmaxf(acc[7], bf_hi(v.w));
        ACCUM(v0) ACCUM(v1) ACCUM(v2) ACCUM(v3)
    }
    for (; e < e1; ++e) {
        int s0 = csr_src[e];
        uint4 v0 = *(const uint4*)&hb[(size_t)s0 * FEAT + q * 8];
        ACCUM(v0)
    }
#undef ACCUM

    uint4 outv;
    if (e1 > e0) {
        outv.x = pack_exact(acc[0], acc[1]);
        outv.y = pack_exact(acc[2], acc[3]);
        outv.z = pack_exact(acc[4], acc[5]);
        outv.w = pack_exact(acc[6], acc[7]);
    } else {
        outv = make_uint4(0, 0, 0, 0);
    }
    *(uint4*)&ab[(size_t)n * FEAT + q * 8] = outv;
}

// ---------------------------------------------------------------------------
// Transform: relu(agg @ Wl^T + h @ Wc^T + bias). thread = node, bf16 inputs,
// f32 weights in LDS (wave-uniform broadcast reads), f32 accumulate.
// BF16OUT: write bf16 intermediate; else f32 (final layer).
// ---------------------------------------------------------------------------
template <bool BF16OUT>
__global__ __launch_bounds__(256) void transform_kernel(const unsigned short* __restrict__ hb,
                                                        const unsigned short* __restrict__ ab,
                                                        const float* __restrict__ Wl,
                                                        const float* __restrict__ Wc,
                                                        const float* __restrict__ bias,
                                                        float* __restrict__ outf,
                                                        unsigned short* __restrict__ outb,
                                                        int nNodes) {
    __shared__ __align__(16) float wl_s[FEAT * FEAT];
    __shared__ __align__(16) float wc_s[FEAT * FEAT];
    __shared__ __align__(16) float b_s[FEAT];

    int tid = threadIdx.x;
#pragma unroll
    for (int i = 0; i < 4; ++i) {
        int idx = (tid + i * 256) * 4;
        *(float4*)&wl_s[idx] = *(const float4*)&Wl[idx];
        *(float4*)&wc_s[idx] = *(const float4*)&Wc[idx];
    }
    if (tid < FEAT) b_s[tid] = bias[tid];
    __syncthreads();

    int n = blockIdx.x * 256 + tid;
    bool valid = (n < nNodes);
    int nc = valid ? n : (nNodes - 1);
    const unsigned short* __restrict__ ar = ab + (size_t)nc * FEAT;
    const unsigned short* __restrict__ hr = hb + (size_t)nc * FEAT;

    float acc[FEAT];
#pragma unroll
    for (int f = 0; f < FEAT; ++f) acc[f] = b_s[f];

#pragma unroll 1
    for (int kc = 0; kc < FEAT; kc += 8) {
        uint4 au = *(const uint4*)(ar + kc);
        uint4 hu = *(const uint4*)(hr + kc);
        float ra[8] = {bf_lo(au.x), bf_hi(au.x), bf_lo(au.y), bf_hi(au.y),
                       bf_lo(au.z), bf_hi(au.z), bf_lo(au.w), bf_hi(au.w)};
        float rh[8] = {bf_lo(hu.x), bf_hi(hu.x), bf_lo(hu.y), bf_hi(hu.y),
                       bf_lo(hu.z), bf_hi(hu.z), bf_lo(hu.w), bf_hi(hu.w)};
#pragma unroll
        for (int f = 0; f < FEAT; ++f) {
            float4 wl0 = *(const float4*)&wl_s[f * FEAT + kc];
            float4 wl1 = *(const float4*)&wl_s[f * FEAT + kc + 4];
            float4 wc0 = *(const float4*)&wc_s[f * FEAT + kc];
            float4 wc1 = *(const float4*)&wc_s[f * FEAT + kc + 4];
            float a = acc[f];
            a = fmaf(ra[0], wl0.x, a); a = fmaf(ra[1], wl0.y, a);
            a = fmaf(ra[2], wl0.z, a); a = fmaf(ra[3], wl0.w, a);
            a = fmaf(ra[4], wl1.x, a); a = fmaf(ra[5], wl1.y, a);
            a = fmaf(ra[6], wl1.z, a); a = fmaf(ra[7], wl1.w, a);
            a = fmaf(rh[0], wc0.x, a); a = fmaf(rh[1], wc0.y, a);
            a = fmaf(rh[2], wc0.z, a); a = fmaf(rh[3], wc0.w, a);
            a = fmaf(rh[4], wc1.x, a); a = fmaf(rh[5], wc1.y, a);
            a = fmaf(rh[6], wc1.z, a); a = fmaf(rh[7], wc1.w, a);
            acc[f] = a;
        }
    }

    if (valid) {
        if (BF16OUT) {
            unsigned short* __restrict__ orow = outb + (size_t)n * FEAT;
#pragma unroll
            for (int f = 0; f < FEAT; f += 8) {
                ushort4 p0 = {f2bf(fmaxf(acc[f],     0.f)), f2bf(fmaxf(acc[f + 1], 0.f)),
                              f2bf(fmaxf(acc[f + 2], 0.f)), f2bf(fmaxf(acc[f + 3], 0.f))};
                ushort4 p1 = {f2bf(fmaxf(acc[f + 4], 0.f)), f2bf(fmaxf(acc[f + 5], 0.f)),
                              f2bf(fmaxf(acc[f + 6], 0.f)), f2bf(fmaxf(acc[f + 7], 0.f))};
                *(ushort4*)(orow + f) = p0;
                *(ushort4*)(orow + f + 4) = p1;
            }
        } else {
            float* __restrict__ orow = outf + (size_t)n * FEAT;
#pragma unroll
            for (int f = 0; f < FEAT; f += 4) {
                float4 v = make_float4(fmaxf(acc[f],     0.f), fmaxf(acc[f + 1], 0.f),
                                       fmaxf(acc[f + 2], 0.f), fmaxf(acc[f + 3], 0.f));
                *(float4*)(orow + f) = v;
            }
        }
    }
}

// ---------------------------------------------------------------------------
extern "C" void kernel_launch(void* const* d_in, const int* in_sizes, int n_in,
                              void* d_out, int out_size, void* d_ws, size_t ws_size,
                              hipStream_t stream) {
    const float* x   = (const float*)d_in[0];
    const int* eidx  = (const int*)d_in[1];
    const int N  = in_sizes[0] / FEAT;
    const int E  = in_sizes[1] / 2;
    const int* src = eidx;
    const int* dst = eidx + E;

    const float* Wl[3]; const float* bl[3]; const float* Wr[3];
    const float* Ws[3]; const float* bs[3];
    for (int li = 0; li < 3; ++li) {
        Wl[li] = (const float*)d_in[2 + 5 * li + 0];
        bl[li] = (const float*)d_in[2 + 5 * li + 1];
        Wr[li] = (const float*)d_in[2 + 5 * li + 2];
        Ws[li] = (const float*)d_in[2 + 5 * li + 3];
        bs[li] = (const float*)d_in[2 + 5 * li + 4];
    }

    auto align256 = [](size_t v) { return (v + 255) & ~(size_t)255; };
    char* ws = (char*)d_ws;
    int* off      = (int*)ws;  ws += align256((size_t)(N + 1) * 4);
    int* cursor   = (int*)ws;  ws += align256((size_t)N * 4);
    int* bsum     = (int*)ws;  ws += align256(64 * 4);
    int* boff     = (int*)ws;  ws += align256(64 * 4);
    float* wcbuf  = (float*)ws; ws += align256(3 * FEAT * FEAT * 4);
    float* biasbuf= (float*)ws; ws += align256(3 * FEAT * 4);
    int* csr_src  = (int*)ws;  ws += align256((size_t)E * 4);
    unsigned short* xb  = (unsigned short*)ws; ws += align256((size_t)N * FEAT * 2);
    unsigned short* ab  = (unsigned short*)ws; ws += align256((size_t)N * FEAT * 2);
    unsigned short* h1b = (unsigned short*)ws; ws += align256((size_t)N * FEAT * 2);
    unsigned short* h2b = (unsigned short*)ws; ws += align256((size_t)N * FEAT * 2);

    const int TB = 256;
    int nBlocks = (N + TB - 1) / TB;
    int nb = (N + SCAN_CHUNK - 1) / SCAN_CHUNK;
    int partBlocks = NXCD * NCHUNKS;

    // ---- CSR build + weight fold + x conversion ----
    zero_kernel<<<nBlocks, TB, 0, stream>>>(cursor, N);
    count_part_kernel<<<partBlocks, TB, 0, stream>>>(dst, cursor, E, N);
    scan_sum_kernel<<<nb, TB, 0, stream>>>(cursor, bsum, N);
    scan_block_kernel<<<1, 64, 0, stream>>>(bsum, boff, nb);
    scan_write_kernel<<<nb, TB, 0, stream>>>(cursor, boff, off, N, E);
    zero_kernel<<<nBlocks, TB, 0, stream>>>(cursor, N);
    scatter_part_kernel<<<partBlocks, TB, 0, stream>>>(src, dst, off, cursor, csr_src, E, N);
    prep_kernel<<<(3 * FEAT * FEAT + TB - 1) / TB, TB, 0, stream>>>(
        Wr[0], Ws[0], bl[0], bs[0], Wr[1], Ws[1], bl[1], bs[1],
        Wr[2], Ws[2], bl[2], bs[2], wcbuf, biasbuf);
    int convBlocks = (N * FEAT / 8 + TB - 1) / TB;
    conv_kernel<<<convBlocks, TB, 0, stream>>>(x, xb, N * FEAT);

    int aggBlocks = (N * 8 + TB - 1) / TB;      // 8-lane group per node
    int trfBlocks = (N + 255) / 256;

    // ---- layer 0 ----
    agg_kernel<<<aggBlocks, TB, 0, stream>>>(xb, off, csr_src, ab, N);
    transform_kernel<true><<<trfBlocks, TB, 0, stream>>>(xb, ab, Wl[0], wcbuf + 0 * 4096,
                                                         biasbuf + 0 * 64, nullptr, h1b, N);
    // ---- layer 1 ----
    agg_kernel<<<aggBlocks, TB, 0, stream>>>(h1b, off, csr_src, ab, N);
    transform_kernel<true><<<trfBlocks, TB, 0, stream>>>(h1b, ab, Wl[1], wcbuf + 1 * 4096,
                                                         biasbuf + 1 * 64, nullptr, h2b, N);
    // ---- layer 2 (f32 output) ----
    agg_kernel<<<aggBlocks, TB, 0, stream>>>(h2b, off, csr_src, ab, N);
    transform_kernel<false><<<trfBlocks, TB, 0, stream>>>(h2b, ab, Wl[2], wcbuf + 2 * 4096,
                                                          biasbuf + 2 * 64, (float*)d_out, nullptr, N);
}

// Round 9
// 319.457 us; speedup vs baseline: 2.7053x; 1.3014x over previous
//
#include <hip/hip_runtime.h>
#include <hip/hip_bf16.h>
#include <math.h>

#define FEAT 64
#define NB_PAD 512          // padded bucket count (nodes/bucket = 256 -> nBkt = ceil(N/256) <= 512)

// ---- bf16 helpers (RNE pack, exact unpack) --------------------------------
__device__ __forceinline__ float bf_lo(unsigned u) { return __uint_as_float(u << 16); }
__device__ __forceinline__ float bf_hi(unsigned u) { return __uint_as_float(u & 0xFFFF0000u); }
__device__ __forceinline__ unsigned short f2bf(float f) {
    unsigned b = __float_as_uint(f);
    return (unsigned short)((b + 0x7FFFu + ((b >> 16) & 1u)) >> 16);
}
__device__ __forceinline__ unsigned pack_exact(float lo, float hi) {
    return (__float_as_uint(lo) >> 16) | (__float_as_uint(hi) & 0xFFFF0000u);
}

// ---------------------------------------------------------------------------
__global__ void zero_kernel(int* __restrict__ p, int n) {
    int i = blockIdx.x * blockDim.x + threadIdx.x;
    if (i < n) p[i] = 0;
}

// ---------------------------------------------------------------------------
// Stage 1: global bucket histogram (bucket = dst >> 8), per-block LDS hist.
// ---------------------------------------------------------------------------
__global__ __launch_bounds__(256) void hist_kernel(const int* __restrict__ dst,
                                                   int* __restrict__ bktCnt, int nE) {
    __shared__ int hist[NB_PAD];
    int t = threadIdx.x;
    hist[t] = 0; hist[t + 256] = 0;
    __syncthreads();
    int chunk = (nE + gridDim.x - 1) / gridDim.x;
    int begin = blockIdx.x * chunk;
    int end = begin + chunk; if (end > nE) end = nE;
    for (int i = begin + t; i < end; i += 256)
        atomicAdd(&hist[dst[i] >> 8], 1);
    __syncthreads();
    if (hist[t])       atomicAdd(&bktCnt[t], hist[t]);
    if (hist[t + 256]) atomicAdd(&bktCnt[t + 256], hist[t + 256]);
}

// ---------------------------------------------------------------------------
// Stage 2: exclusive scan of NB_PAD bucket counts -> bktBase, init bktCursor.
// ---------------------------------------------------------------------------
__global__ void bucket_scan_kernel(const int* __restrict__ bktCnt,
                                   int* __restrict__ bktBase,
                                   int* __restrict__ bktCursor) {
    __shared__ int wsum[4];
    int t = threadIdx.x;
    int d0 = bktCnt[2 * t], d1 = bktCnt[2 * t + 1];
    int ps = d0 + d1;
    int lane = t & 63, w = t >> 6;
    int inc = ps;
    for (int d = 1; d < 64; d <<= 1) { int tt = __shfl_up(inc, d); if (lane >= d) inc += tt; }
    if (lane == 63) wsum[w] = inc;
    __syncthreads();
    if (t == 0) { int r = 0; for (int k = 0; k < 4; ++k) { int v = wsum[k]; wsum[k] = r; r += v; } }
    __syncthreads();
    int pexc = (inc - ps) + wsum[w];
    bktBase[2 * t] = pexc;        bktCursor[2 * t] = pexc;
    bktBase[2 * t + 1] = pexc + d0; bktCursor[2 * t + 1] = pexc + d0;
}

// ---------------------------------------------------------------------------
// Stage 3: partition edges into per-bucket (src,dst) pair arrays.
// Per-block LDS hist -> one global reservation per (block,bucket) -> LDS-rank
// writes. Hot atomics are all LDS.
// ---------------------------------------------------------------------------
__global__ __launch_bounds__(256) void partition_kernel(const int* __restrict__ src,
                                                        const int* __restrict__ dst,
                                                        int* __restrict__ bktCursor,
                                                        uint2* __restrict__ pairs, int nE) {
    __shared__ int hist[NB_PAD];
    __shared__ int lofs[NB_PAD];
    int t = threadIdx.x;
    hist[t] = 0; hist[t + 256] = 0;
    __syncthreads();
    int chunk = (nE + gridDim.x - 1) / gridDim.x;
    int begin = blockIdx.x * chunk;
    int end = begin + chunk; if (end > nE) end = nE;
    for (int i = begin + t; i < end; i += 256)
        atomicAdd(&hist[dst[i] >> 8], 1);
    __syncthreads();
    int c0 = hist[t], c1 = hist[t + 256];
    lofs[t]       = c0 ? atomicAdd(&bktCursor[t], c0) : 0;
    lofs[t + 256] = c1 ? atomicAdd(&bktCursor[t + 256], c1) : 0;
    __syncthreads();
    for (int i = begin + t; i < end; i += 256) {
        int d = dst[i];
        int pos = atomicAdd(&lofs[d >> 8], 1);
        pairs[pos] = make_uint2((unsigned)src[i], (unsigned)d);
    }
}

// ---------------------------------------------------------------------------
// Stage 4: per-bucket CSR finalize. Block b owns nodes [b*256, b*256+256) and
// edges [bktBase[b], bktBase[b+1]). LDS degree count -> LDS scan -> off[],
// then LDS-cursor scatter of src into the bucket's contiguous csr region.
// ---------------------------------------------------------------------------
__global__ __launch_bounds__(256) void csr_bucket_kernel(const uint2* __restrict__ pairs,
                                                         const int* __restrict__ bktBase,
                                                         int* __restrict__ off,
                                                         int* __restrict__ csr,
                                                         int N, int E) {
    __shared__ int deg[256];
    __shared__ int cur[256];
    __shared__ int wsum[4];
    int b = blockIdx.x;
    int t = threadIdx.x;
    int lo = b << 8;
    int nloc = N - lo; if (nloc > 256) nloc = 256;
    int e0 = bktBase[b], e1 = bktBase[b + 1];
    deg[t] = 0;
    __syncthreads();
    for (int e = e0 + t; e < e1; e += 256)
        atomicAdd(&deg[(int)pairs[e].y - lo], 1);
    __syncthreads();
    int v = deg[t];
    int lane = t & 63, w = t >> 6;
    int inc = v;
    for (int d = 1; d < 64; d <<= 1) { int tt = __shfl_up(inc, d); if (lane >= d) inc += tt; }
    if (lane == 63) wsum[w] = inc;
    __syncthreads();
    if (t == 0) { int r = 0; for (int k = 0; k < 4; ++k) { int x = wsum[k]; wsum[k] = r; r += x; } }
    __syncthreads();
    int excl = (inc - v) + wsum[w];
    if (t < nloc) off[lo + t] = e0 + excl;
    cur[t] = excl;
    if (b == 0 && t == 0) off[N] = E;
    __syncthreads();
    for (int e = e0 + t; e < e1; e += 256) {
        uint2 p = pairs[e];
        int pos = atomicAdd(&cur[(int)p.y - lo], 1);
        csr[e0 + pos] = (int)p.x;
    }
}

// ---------------------------------------------------------------------------
// prep: Wc = Wr+Ws, bias = bl+bs (f32)
// ---------------------------------------------------------------------------
__global__ void prep_kernel(const float* __restrict__ Wr0, const float* __restrict__ Ws0,
                            const float* __restrict__ bl0, const float* __restrict__ bs0,
                            const float* __restrict__ Wr1, const float* __restrict__ Ws1,
                            const float* __restrict__ bl1, const float* __restrict__ bs1,
                            const float* __restrict__ Wr2, const float* __restrict__ Ws2,
                            const float* __restrict__ bl2, const float* __restrict__ bs2,
                            float* __restrict__ wc, float* __restrict__ bias) {
    int i = blockIdx.x * blockDim.x + threadIdx.x;
    if (i < 3 * FEAT * FEAT) {
        int li = i >> 12, j = i & 4095;
        const float* Wr = (li == 0) ? Wr0 : (li == 1) ? Wr1 : Wr2;
        const float* Ws = (li == 0) ? Ws0 : (li == 1) ? Ws1 : Ws2;
        wc[i] = Wr[j] + Ws[j];
    }
    if (i < 3 * FEAT) {
        int li = i >> 6, j = i & 63;
        const float* bl = (li == 0) ? bl0 : (li == 1) ? bl1 : bl2;
        const float* bs = (li == 0) ? bs0 : (li == 1) ? bs1 : bs2;
        bias[i] = bl[j] + bs[j];
    }
}

// ---------------------------------------------------------------------------
// x (f32) -> xb (bf16), 8 elems/thread
// ---------------------------------------------------------------------------
__global__ __launch_bounds__(256) void conv_kernel(const float* __restrict__ in,
                                                   unsigned short* __restrict__ outb,
                                                   int nElem) {
    int base = (blockIdx.x * blockDim.x + threadIdx.x) * 8;
    if (base >= nElem) return;
    float4 a = *(const float4*)(in + base);
    float4 b = *(const float4*)(in + base + 4);
    ushort4 p0 = {f2bf(a.x), f2bf(a.y), f2bf(a.z), f2bf(a.w)};
    ushort4 p1 = {f2bf(b.x), f2bf(b.y), f2bf(b.z), f2bf(b.w)};
    *(ushort4*)(outb + base) = p0;
    *(ushort4*)(outb + base + 4) = p1;
}

// ---------------------------------------------------------------------------
// Max-aggregation on bf16 rows (128 B/row): 8-lane group per node.
// ---------------------------------------------------------------------------
__global__ __launch_bounds__(256) void agg_kernel(const unsigned short* __restrict__ hb,
                                                  const int* __restrict__ off,
                                                  const int* __restrict__ csr_src,
                                                  unsigned short* __restrict__ ab,
                                                  int nNodes) {
    int gid = blockIdx.x * blockDim.x + threadIdx.x;
    int n = gid >> 3;
    int q = gid & 7;
    if (n >= nNodes) return;

    int e0 = off[n], e1 = off[n + 1];
    const float NEG = -INFINITY;
    float acc[8] = {NEG, NEG, NEG, NEG, NEG, NEG, NEG, NEG};

    int e = e0;
    for (; e + 4 <= e1; e += 4) {
        int s0 = csr_src[e], s1 = csr_src[e + 1], s2 = csr_src[e + 2], s3 = csr_src[e + 3];
        uint4 v0 = *(const uint4*)&hb[(size_t)s0 * FEAT + q * 8];
        uint4 v1 = *(const uint4*)&hb[(size_t)s1 * FEAT + q * 8];
        uint4 v2 = *(const uint4*)&hb[(size_t)s2 * FEAT + q * 8];
        uint4 v3 = *(const uint4*)&hb[(size_t)s3 * FEAT + q * 8];
#define ACCUM(v)                                            \
        acc[0] = fmaxf(acc[0], bf_lo(v.x)); acc[1] = fmaxf(acc[1], bf_hi(v.x)); \
        acc[2] = fmaxf(acc[2], bf_lo(v.y)); acc[3] = fmaxf(acc[3], bf_hi(v.y)); \
        acc[4] = fmaxf(acc[4], bf_lo(v.z)); acc[5] = fmaxf(acc[5], bf_hi(v.z)); \
        acc[6] = fmaxf(acc[6], bf_lo(v.w)); acc[7] = fmaxf(acc[7], bf_hi(v.w));
        ACCUM(v0) ACCUM(v1) ACCUM(v2) ACCUM(v3)
    }
    for (; e < e1; ++e) {
        int s0 = csr_src[e];
        uint4 v0 = *(const uint4*)&hb[(size_t)s0 * FEAT + q * 8];
        ACCUM(v0)
    }
#undef ACCUM

    uint4 outv;
    if (e1 > e0) {
        outv.x = pack_exact(acc[0], acc[1]);
        outv.y = pack_exact(acc[2], acc[3]);
        outv.z = pack_exact(acc[4], acc[5]);
        outv.w = pack_exact(acc[6], acc[7]);
    } else {
        outv = make_uint4(0, 0, 0, 0);
    }
    *(uint4*)&ab[(size_t)n * FEAT + q * 8] = outv;
}

// ---------------------------------------------------------------------------
// Transform: relu(agg @ Wl^T + h @ Wc^T + bias). thread = node, bf16 inputs,
// f32 weights in LDS (wave-uniform broadcast reads), f32 accumulate.
// ---------------------------------------------------------------------------
template <bool BF16OUT>
__global__ __launch_bounds__(256) void transform_kernel(const unsigned short* __restrict__ hb,
                                                        const unsigned short* __restrict__ ab,
                                                        const float* __restrict__ Wl,
                                                        const float* __restrict__ Wc,
                                                        const float* __restrict__ bias,
                                                        float* __restrict__ outf,
                                                        unsigned short* __restrict__ outb,
                                                        int nNodes) {
    __shared__ __align__(16) float wl_s[FEAT * FEAT];
    __shared__ __align__(16) float wc_s[FEAT * FEAT];
    __shared__ __align__(16) float b_s[FEAT];

    int tid = threadIdx.x;
#pragma unroll
    for (int i = 0; i < 4; ++i) {
        int idx = (tid + i * 256) * 4;
        *(float4*)&wl_s[idx] = *(const float4*)&Wl[idx];
        *(float4*)&wc_s[idx] = *(const float4*)&Wc[idx];
    }
    if (tid < FEAT) b_s[tid] = bias[tid];
    __syncthreads();

    int n = blockIdx.x * 256 + tid;
    bool valid = (n < nNodes);
    int nc = valid ? n : (nNodes - 1);
    const unsigned short* __restrict__ ar = ab + (size_t)nc * FEAT;
    const unsigned short* __restrict__ hr = hb + (size_t)nc * FEAT;

    float acc[FEAT];
#pragma unroll
    for (int f = 0; f < FEAT; ++f) acc[f] = b_s[f];

#pragma unroll 1
    for (int kc = 0; kc < FEAT; kc += 8) {
        uint4 au = *(const uint4*)(ar + kc);
        uint4 hu = *(const uint4*)(hr + kc);
        float ra[8] = {bf_lo(au.x), bf_hi(au.x), bf_lo(au.y), bf_hi(au.y),
                       bf_lo(au.z), bf_hi(au.z), bf_lo(au.w), bf_hi(au.w)};
        float rh[8] = {bf_lo(hu.x), bf_hi(hu.x), bf_lo(hu.y), bf_hi(hu.y),
                       bf_lo(hu.z), bf_hi(hu.z), bf_lo(hu.w), bf_hi(hu.w)};
#pragma unroll
        for (int f = 0; f < FEAT; ++f) {
            float4 wl0 = *(const float4*)&wl_s[f * FEAT + kc];
            float4 wl1 = *(const float4*)&wl_s[f * FEAT + kc + 4];
            float4 wc0 = *(const float4*)&wc_s[f * FEAT + kc];
            float4 wc1 = *(const float4*)&wc_s[f * FEAT + kc + 4];
            float a = acc[f];
            a = fmaf(ra[0], wl0.x, a); a = fmaf(ra[1], wl0.y, a);
            a = fmaf(ra[2], wl0.z, a); a = fmaf(ra[3], wl0.w, a);
            a = fmaf(ra[4], wl1.x, a); a = fmaf(ra[5], wl1.y, a);
            a = fmaf(ra[6], wl1.z, a); a = fmaf(ra[7], wl1.w, a);
            a = fmaf(rh[0], wc0.x, a); a = fmaf(rh[1], wc0.y, a);
            a = fmaf(rh[2], wc0.z, a); a = fmaf(rh[3], wc0.w, a);
            a = fmaf(rh[4], wc1.x, a); a = fmaf(rh[5], wc1.y, a);
            a = fmaf(rh[6], wc1.z, a); a = fmaf(rh[7], wc1.w, a);
            acc[f] = a;
        }
    }

    if (valid) {
        if (BF16OUT) {
            unsigned short* __restrict__ orow = outb + (size_t)n * FEAT;
#pragma unroll
            for (int f = 0; f < FEAT; f += 8) {
                ushort4 p0 = {f2bf(fmaxf(acc[f],     0.f)), f2bf(fmaxf(acc[f + 1], 0.f)),
                              f2bf(fmaxf(acc[f + 2], 0.f)), f2bf(fmaxf(acc[f + 3], 0.f))};
                ushort4 p1 = {f2bf(fmaxf(acc[f + 4], 0.f)), f2bf(fmaxf(acc[f + 5], 0.f)),
                              f2bf(fmaxf(acc[f + 6], 0.f)), f2bf(fmaxf(acc[f + 7], 0.f))};
                *(ushort4*)(orow + f) = p0;
                *(ushort4*)(orow + f + 4) = p1;
            }
        } else {
            float* __restrict__ orow = outf + (size_t)n * FEAT;
#pragma unroll
            for (int f = 0; f < FEAT; f += 4) {
                float4 v = make_float4(fmaxf(acc[f],     0.f), fmaxf(acc[f + 1], 0.f),
                                       fmaxf(acc[f + 2], 0.f), fmaxf(acc[f + 3], 0.f));
                *(float4*)(orow + f) = v;
            }
        }
    }
}

// ---------------------------------------------------------------------------
extern "C" void kernel_launch(void* const* d_in, const int* in_sizes, int n_in,
                              void* d_out, int out_size, void* d_ws, size_t ws_size,
                              hipStream_t stream) {
    const float* x   = (const float*)d_in[0];
    const int* eidx  = (const int*)d_in[1];
    const int N  = in_sizes[0] / FEAT;
    const int E  = in_sizes[1] / 2;
    const int* src = eidx;
    const int* dst = eidx + E;

    const float* Wl[3]; const float* bl[3]; const float* Wr[3];
    const float* Ws[3]; const float* bs[3];
    for (int li = 0; li < 3; ++li) {
        Wl[li] = (const float*)d_in[2 + 5 * li + 0];
        bl[li] = (const float*)d_in[2 + 5 * li + 1];
        Wr[li] = (const float*)d_in[2 + 5 * li + 2];
        Ws[li] = (const float*)d_in[2 + 5 * li + 3];
        bs[li] = (const float*)d_in[2 + 5 * li + 4];
    }

    auto align256 = [](size_t v) { return (v + 255) & ~(size_t)255; };
    char* ws = (char*)d_ws;
    int* off       = (int*)ws;  ws += align256((size_t)(N + 1) * 4);
    int* bktCnt    = (int*)ws;  ws += align256(NB_PAD * 4);
    int* bktBase   = (int*)ws;  ws += align256((NB_PAD + 1) * 4);
    int* bktCursor = (int*)ws;  ws += align256(NB_PAD * 4);
    uint2* pairs   = (uint2*)ws; ws += align256((size_t)E * 8);
    int* csr_src   = (int*)ws;  ws += align256((size_t)E * 4);
    float* wcbuf   = (float*)ws; ws += align256(3 * FEAT * FEAT * 4);
    float* biasbuf = (float*)ws; ws += align256(3 * FEAT * 4);
    unsigned short* xb  = (unsigned short*)ws; ws += align256((size_t)N * FEAT * 2);
    unsigned short* ab  = (unsigned short*)ws; ws += align256((size_t)N * FEAT * 2);
    unsigned short* h1b = (unsigned short*)ws; ws += align256((size_t)N * FEAT * 2);
    unsigned short* h2b = (unsigned short*)ws; ws += align256((size_t)N * FEAT * 2);

    const int TB = 256;
    int nBkt = (N + 255) >> 8;          // 391 for N=100000 (<= NB_PAD)

    // ---- CSR build: hist -> scan -> partition -> per-bucket finalize ----
    zero_kernel<<<2, TB, 0, stream>>>(bktCnt, NB_PAD);
    hist_kernel<<<256, TB, 0, stream>>>(dst, bktCnt, E);
    bucket_scan_kernel<<<1, TB, 0, stream>>>(bktCnt, bktBase, bktCursor);
    partition_kernel<<<256, TB, 0, stream>>>(src, dst, bktCursor, pairs, E);
    csr_bucket_kernel<<<nBkt, TB, 0, stream>>>(pairs, bktBase, off, csr_src, N, E);

    prep_kernel<<<(3 * FEAT * FEAT + TB - 1) / TB, TB, 0, stream>>>(
        Wr[0], Ws[0], bl[0], bs[0], Wr[1], Ws[1], bl[1], bs[1],
        Wr[2], Ws[2], bl[2], bs[2], wcbuf, biasbuf);
    int convBlocks = (N * FEAT / 8 + TB - 1) / TB;
    conv_kernel<<<convBlocks, TB, 0, stream>>>(x, xb, N * FEAT);

    int aggBlocks = (N * 8 + TB - 1) / TB;
    int trfBlocks = (N + 255) / 256;

    // ---- layer 0 ----
    agg_kernel<<<aggBlocks, TB, 0, stream>>>(xb, off, csr_src, ab, N);
    transform_kernel<true><<<trfBlocks, TB, 0, stream>>>(xb, ab, Wl[0], wcbuf + 0 * 4096,
                                                         biasbuf + 0 * 64, nullptr, h1b, N);
    // ---- layer 1 ----
    agg_kernel<<<aggBlocks, TB, 0, stream>>>(h1b, off, csr_src, ab, N);
    transform_kernel<true><<<trfBlocks, TB, 0, stream>>>(h1b, ab, Wl[1], wcbuf + 1 * 4096,
                                                         biasbuf + 1 * 64, nullptr, h2b, N);
    // ---- layer 2 (f32 output) ----
    agg_kernel<<<aggBlocks, TB, 0, stream>>>(h2b, off, csr_src, ab, N);
    transform_kernel<false><<<trfBlocks, TB, 0, stream>>>(h2b, ab, Wl[2], wcbuf + 2 * 4096,
                                                          biasbuf + 2 * 64, (float*)d_out, nullptr, N);
}